// Round 6
// baseline (239.775 us; speedup 1.0000x reference)
//
#include <hip/hip_runtime.h>
#include <math.h>

#define D_DIM 256
#define HW 16384
#define C 19
#define N_PX 131072
#define EPS 1e-8f

#define S_SC  1048576.0f       // 2^20 fixed point for class sums (|sum| < ~500)
#define IS_S  (1.0f/1048576.0f)
#define U_SC  16777216.0f      // 2^24 fixed point for unit-vector sums (|sum| < ~30)
#define IS_U  (1.0f/16777216.0f)

// ws layout in 4-byte words
#define OFF_S     0        // int[4864]   class sums Σf, fixed-point
#define OFF_U     4864     // int[4864]   class unit sums Σf/||f||, fixed-point
#define OFF_CNT   9728     // int[19]     class counts
#define WS_ZERO   9747
#define OFF_INORM 9760     // float[131072]  U_SC/||f_px||
#define OFF_PART  141312   // int[2048][2432] per-(chunk,slice) partials (20 MB), 16B aligned
#define PROW      2432     // words per partial row: S(19*64) | U(19*64)

// ---------- K0: zero final accumulators ----------
__global__ void k0_zero(int* __restrict__ ws) {
    int i = blockIdx.x * blockDim.x + threadIdx.x;
    if (i < WS_ZERO) ws[i] = 0;
}

// ---------- kA: per-pixel U_SC/||f|| + class counts. Pure stream, 2KB LDS, grid 1024 ----------
// block owns 128 px; 256 thr = 64 px-pairs (q) x 4 d-quarters (dq, 64 d each).
__global__ __launch_bounds__(256) void kA_norm(const float* __restrict__ in,
                                               const int* __restrict__ tgt,
                                               int* __restrict__ wsi) {
    __shared__ __align__(16) float s_nfp[64 * 8];  // per-px-pair partials, 4 dq each
    __shared__ int s_cnt[C];
    const int tid = threadIdx.x;
    const int q   = tid & 63;
    const int dq  = tid >> 6;
    if (tid < C) s_cnt[tid] = 0;
    __syncthreads();

    const int px0 = blockIdx.x << 7;          // 128 px per block
    const int b   = px0 >> 14;
    const int p   = px0 + (q << 1);
    if (dq == 0) {
        atomicAdd(&s_cnt[tgt[p]], 1);
        atomicAdd(&s_cnt[tgt[p + 1]], 1);
    }

    const float* base = in + (((size_t)(b * D_DIM + (dq << 6))) << 14)
                           + (px0 & (HW - 1)) + (q << 1);
    float nfa = 0.f, nfb = 0.f;
    #pragma unroll
    for (int g = 0; g < 8; ++g) {
        float2 v[8];
        #pragma unroll
        for (int j = 0; j < 8; ++j)
            v[j] = *(const float2*)(base + ((size_t)(g * 8 + j) << 14));
        #pragma unroll
        for (int j = 0; j < 8; ++j) {
            nfa += v[j].x * v[j].x; nfb += v[j].y * v[j].y;
        }
    }
    s_nfp[(q << 3) + dq]     = nfa;
    s_nfp[(q << 3) + 4 + dq] = nfb;
    __syncthreads();

    if (tid < 64) {                            // one wave finishes 128 px
        const float4 na4 = *(const float4*)&s_nfp[tid << 3];
        const float4 nb4 = *(const float4*)&s_nfp[(tid << 3) + 4];
        const float na = na4.x + na4.y + na4.z + na4.w;
        const float nb = nb4.x + nb4.y + nb4.z + nb4.w;
        float2 io;
        io.x = na > 0.f ? U_SC / sqrtf(na) : 0.f;
        io.y = nb > 0.f ? U_SC / sqrtf(nb) : 0.f;
        *(float2*)((float*)wsi + OFF_INORM + px0 + (tid << 1)) = io;
    }
    if (tid < C) atomicAdd(&wsi[OFF_CNT + tid], s_cnt[tid]);
}

// ---------- kB: d-sliced S/U accumulation. 10KB LDS -> 8 blocks/CU, 32 waves ----------
// grid (512, 4): x = 256-px chunk, y = 64-d slice. 256 thr = 64 q x 4 dq (16 d each), 2 px-rounds.
__global__ __launch_bounds__(256) void kB_accum(const float* __restrict__ in,
                                                const int* __restrict__ tgt,
                                                int* __restrict__ wsi) {
    __shared__ int sS[C * 65];     // stride 65 (%32==1): same-d lanes, distinct labels -> distinct banks
    __shared__ int sU[C * 65];
    const int tid = threadIdx.x;
    const int q   = tid & 63;
    const int dq  = tid >> 6;
    for (int i = tid; i < C * 65; i += 256) { sS[i] = 0; sU[i] = 0; }
    __syncthreads();

    const int px0   = blockIdx.x << 8;        // 256 px per chunk
    const int slice = blockIdx.y;
    const int b     = px0 >> 14;
    const float* inormf = (const float*)wsi + OFF_INORM;

    #pragma unroll
    for (int r = 0; r < 2; ++r) {
        const int p  = px0 + (r << 7) + (q << 1);
        const int la = tgt[p], lb = tgt[p + 1];
        const float2 io = *(const float2*)(inormf + p);
        const float* base = in
            + (((size_t)(b * D_DIM + (slice << 6) + (dq << 4))) << 14)
            + (px0 & (HW - 1)) + (r << 7) + (q << 1);

        #pragma unroll
        for (int g = 0; g < 2; ++g) {
            float2 v[8];
            #pragma unroll
            for (int j = 0; j < 8; ++j)
                v[j] = *(const float2*)(base + ((size_t)(g * 8 + j) << 14));
            #pragma unroll
            for (int j = 0; j < 8; ++j) {
                const int ds = (dq << 4) + g * 8 + j;   // d within slice, same for all lanes
                atomicAdd(&sS[la * 65 + ds], __float2int_rn(v[j].x * S_SC));
                atomicAdd(&sS[lb * 65 + ds], __float2int_rn(v[j].y * S_SC));
                atomicAdd(&sU[la * 65 + ds], __float2int_rn(v[j].x * io.x));
                atomicAdd(&sU[lb * 65 + ds], __float2int_rn(v[j].y * io.y));
            }
        }
    }
    __syncthreads();

    // plain coalesced partial-row writeout
    int* __restrict__ row = wsi + OFF_PART + (size_t)(slice * 512 + blockIdx.x) * PROW;
    for (int i = tid; i < C * 64; i += 256) {
        int c = i >> 6, ds = i & 63;
        row[i]           = sS[c * 65 + ds];
        row[C * 64 + i]  = sU[c * 65 + ds];
    }
}

// ---------- k1b: reduce 512 chunk-rows per slice -> final S/U ----------
// grid (3, 64): x covers 608 int4 columns, y = slice(4) x row-group(16 of 32 rows).
__global__ __launch_bounds__(256) void k1b_reduce(int* __restrict__ wsi) {
    const int c4 = blockIdx.x * 256 + threadIdx.x;
    if (c4 >= PROW / 4) return;
    const int slice = blockIdx.y >> 4;
    const int rg    = blockIdx.y & 15;
    const int4* base = (const int4*)(wsi + OFF_PART)
                     + ((size_t)slice * 512 + rg * 32) * (PROW / 4) + c4;
    int4 acc = {0, 0, 0, 0};
    #pragma unroll
    for (int r = 0; r < 32; ++r) {
        int4 v = base[(size_t)r * (PROW / 4)];
        acc.x += v.x; acc.y += v.y; acc.z += v.z; acc.w += v.w;
    }
    const int isU = c4 >= 304;
    const int j   = c4 - (isU ? 304 : 0);
    const int c   = j >> 4;
    const int dd4 = j & 15;
    int* dst = wsi + (isU ? OFF_U : OFF_S) + c * D_DIM + (slice << 6) + (dd4 << 2);
    atomicAdd(dst + 0, acc.x);
    atomicAdd(dst + 1, acc.y);
    atomicAdd(dst + 2, acc.z);
    atomicAdd(dst + 3, acc.w);
}

// ---------- k2: centers, norms, Gram/diff, sim, final (1 block) ----------
__global__ __launch_bounds__(512) void k2_final(const int* __restrict__ wsi,
                                                float* __restrict__ out) {
    __shared__ __align__(16) float s_cen[C * 260];
    __shared__ __align__(16) float s_u[C * 260];
    __shared__ float s_nc[C];
    __shared__ float s_cntf[C];
    __shared__ float s_pair[C * C];
    __shared__ float s_sim[C];
    const int tid = threadIdx.x;

    if (tid < C) s_cntf[tid] = (float)wsi[OFF_CNT + tid];
    __syncthreads();
    for (int i = tid; i < C * 256; i += 512) {
        int c = i >> 8, d = i & 255;
        float icnt = 1.f / fmaxf(s_cntf[c], 1.f);
        s_cen[c * 260 + d] = (float)wsi[OFF_S + i] * IS_S * icnt;
        s_u[c * 260 + d]   = (float)wsi[OFF_U + i] * IS_U;
    }
    __syncthreads();
    if (tid < C) {
        float nsq = 0.f;
        for (int d = 0; d < D_DIM; ++d) {
            float x = s_cen[tid * 260 + d];
            nsq += x * x;
        }
        s_nc[tid] = sqrtf(nsq);
    }
    __syncthreads();
    if (tid < C * C) {
        int i = tid / C, j = tid % C;
        const float4* ci = (const float4*)&s_cen[i * 260];
        const float4* cj = (const float4*)&s_cen[j * 260];
        float dot = 0.f;
        #pragma unroll 8
        for (int k = 0; k < 64; ++k) {
            float4 a = ci[k], bb = cj[k];
            dot += a.x * bb.x + a.y * bb.y + a.z * bb.z + a.w * bb.w;
        }
        float S = dot / fmaxf(s_nc[i] * s_nc[j], EPS);
        s_pair[tid] = (i == j) ? (1.f - S) : fmaxf(S, 0.f);
    } else if (tid >= 384 && tid < 384 + C) {
        int i = tid - 384;
        const float4* ci = (const float4*)&s_cen[i * 260];
        const float4* ui = (const float4*)&s_u[i * 260];
        float dot = 0.f;
        #pragma unroll 8
        for (int k = 0; k < 64; ++k) {
            float4 a = ci[k], bb = ui[k];
            dot += a.x * bb.x + a.y * bb.y + a.z * bb.z + a.w * bb.w;
        }
        s_sim[i] = (s_cntf[i] > 0.f)
                 ? (1.f - dot / fmaxf(s_nc[i] * s_cntf[i], EPS)) : 0.f;
    }
    __syncthreads();
    if (tid < C) {
        float row = 0.f;
        for (int j = 0; j < C; ++j) row += s_pair[tid * C + j];
        s_pair[tid * C] = (s_cntf[tid] > 0.f) ? (row * (1.f / (float)C)) : 0.f;
    }
    __syncthreads();
    if (tid == 0) {
        float tot = 0.f;
        for (int i = 0; i < C; ++i) tot += s_pair[i * C] + s_sim[i];
        out[0] = tot;
    }
}

extern "C" void kernel_launch(void* const* d_in, const int* in_sizes, int n_in,
                              void* d_out, int out_size, void* d_ws, size_t ws_size,
                              hipStream_t stream) {
    const float* in  = (const float*)d_in[0];
    const int*   tgt = (const int*)d_in[1];
    float* out = (float*)d_out;
    int*   wsi = (int*)d_ws;

    k0_zero<<<39, 256, 0, stream>>>(wsi);
    kA_norm<<<1024, 256, 0, stream>>>(in, tgt, wsi);
    kB_accum<<<dim3(512, 4), 256, 0, stream>>>(in, tgt, wsi);
    k1b_reduce<<<dim3(3, 64), 256, 0, stream>>>(wsi);
    k2_final<<<1, 512, 0, stream>>>(wsi, out);
}